// Round 7
// baseline (115.734 us; speedup 1.0000x reference)
//
#include <hip/hip_runtime.h>
#include <hip/hip_bf16.h>

// Problem constants (fixed by setup_inputs)
constexpr int B = 512;   // batch
constexpr int D = 4096;  // D_vis
constexpr int E = 1024;  // embed dim
constexpr int N = 512;   // negatives
constexpr int KC = 512;  // K per wave (8 waves cover D=4096)
constexpr int NSTEP = KC / 32;  // 16 k-steps per wave
constexpr int ES = 8;    // scores E-split factor
constexpr int EC = E / ES;      // 128 e per scores block
constexpr int DEPTH = 2;        // GEMM pipeline depth per wave

typedef __attribute__((ext_vector_type(8))) short bf16x8;   // 8 bf16 = 4 VGPRs
typedef __attribute__((ext_vector_type(4))) float f32x4;
typedef _Float16 h2 __attribute__((ext_vector_type(2)));
typedef _Float16 h4 __attribute__((ext_vector_type(4)));
typedef _Float16 h8 __attribute__((ext_vector_type(8)));

typedef __attribute__((address_space(3))) void lds_void;
typedef const __attribute__((address_space(1))) void gbl_void;

__device__ __forceinline__ unsigned short f2bf(float f) {
    __hip_bfloat16 h = __float2bfloat16(f);   // RTNE
    return *reinterpret_cast<unsigned short*>(&h);
}

#if __has_builtin(__builtin_amdgcn_fdot2)
__device__ __forceinline__ float fdot2(h2 a, h2 b, float c) {
    return __builtin_amdgcn_fdot2(a, b, c, false);
}
#else
__device__ __forceinline__ float fdot2(h2 a, h2 b, float c) {
    return c + (float)a[0] * (float)b[0] + (float)a[1] * (float)b[1];
}
#endif

// ---------------------------------------------------------------------------
// Kernel 0: f32 -> bf16 convert for vf and W; block 3072 zeroes psum[512].
// grid 3073: [0,1024) vf, [1024,3072) W, 3072 psum-zero.
// ---------------------------------------------------------------------------
__global__ __launch_bounds__(256) void cvt_all(
    const float* __restrict__ vf, const float* __restrict__ W,
    unsigned short* __restrict__ vfB, unsigned short* __restrict__ WB,
    float* __restrict__ psum)
{
    const int bid = blockIdx.x;
    if (bid == 3072) {
        if (threadIdx.x < 128)
            ((f32x4*)psum)[threadIdx.x] = (f32x4){0.f, 0.f, 0.f, 0.f};
        return;
    }
    const float* src;
    unsigned short* dst;
    int i;
    if (bid < 1024) { src = vf; dst = vfB; i = (bid * 256 + threadIdx.x) * 8; }
    else           { src = W;  dst = WB;  i = ((bid - 1024) * 256 + threadIdx.x) * 8; }
    float4 v0 = *(const float4*)(src + i);
    float4 v1 = *(const float4*)(src + i + 4);
    bf16x8 o;
    o[0] = (short)f2bf(v0.x); o[1] = (short)f2bf(v0.y);
    o[2] = (short)f2bf(v0.z); o[3] = (short)f2bf(v0.w);
    o[4] = (short)f2bf(v1.x); o[5] = (short)f2bf(v1.y);
    o[6] = (short)f2bf(v1.z); o[7] = (short)f2bf(v1.w);
    *(bf16x8*)(dst + i) = o;
}

// ---------------------------------------------------------------------------
// Kernel 1 (r7): FULL-K fused GEMM + bias + emb16 + positive-score partial.
// grid 256 blocks x 8 waves (512 thr) = 1 block/CU, 8 waves/CU (2/SIMD).
// Tile 32(m) x 64(n); wave w covers K-chunk [w*512, w*512+512) with the
// verified per-wave pipeline (DEPTH=2, 6 gload_lds/step: A=2 chunks, B=4;
// steady vmcnt(6), last step vmcnt(0)). Per-wave LDS: A 2x2KB + B 2x4KB
// = 12KB -> 96KB/block staging.
// Epilogue: barrier -> per-wave 32x69 f32 transpose buffers (stride 69:
// 69%32=5, gcd(5,32)=1 -> conflict-free; 8x8832B = 70656B overlays dead
// staging) -> barrier -> 512 threads sum 8 partials in f32, add bias,
// write emb16 (f16), compute relu(p_lfs-s)^2 partial and atomicAdd one
// f32 per row into psum (full-precision f32 path for positives).
// This ELIMINATES pg (8MB round-trip) and the reduce_emb dispatch.
//  XCD swizzle: id in [0,256), xcd=id&7 owns an 8m x 4n super-tile:
//  m0=((xcd>>2)*8+(w8&7))*32, n0=((xcd&3)*4+(w8>>3))*64, w8=id>>3.
//  Per-XCD ws = 2MB A + 2MB B ~ L2.
// LDS staging layout + fragment mapping unchanged (verified prior session).
// C/D: col=lane&15, row=quad*4+reg.
// ---------------------------------------------------------------------------
__global__ __launch_bounds__(512, 2) void gemm_fused(
    const unsigned short* __restrict__ vf,    // [B, D] bf16 bits
    const unsigned short* __restrict__ W,     // [E, D] bf16 bits
    const float* __restrict__ bias,           // [E]
    const float* __restrict__ p_lfs,          // [B, E] f32
    _Float16* __restrict__ emb16,             // [B, E] f16
    float* __restrict__ psum)                 // [B] f32 (pre-zeroed)
{
    // [w*12K, w*12K+4K) = wave w sA (2 x 2KB); +4K..+12K = sB (2 x 4KB).
    // Epilogue overlays [0, 70656) as 8 x (32x69 f32) buffers.
    __shared__ __align__(16) char smem[98304];

    const int t = threadIdx.x;
    const int w = t >> 6;        // wave 0..7
    const int L = t & 63;

    const int id  = blockIdx.x;          // [0,256)
    const int xcd = id & 7;
    const int w8  = id >> 3;             // [0,32)
    const int m0 = ((xcd >> 2) * 8 + (w8 & 7)) * 32;
    const int n0 = ((xcd & 3) * 4 + (w8 >> 3)) * 64;

    char* stg = smem + w * 12288;        // this wave's staging base

    // ---- staging addresses ----
    const int subrow = L >> 2;                                  // 0..15
    const int qstg = (L & 3) ^ ((L >> 2) & 3) ^ ((L >> 4) & 3); // swizzled k-group
    const int kbeg = w * KC;
    const unsigned short* aSrc[2];
    const unsigned short* bSrc[4];
    #pragma unroll
    for (int c = 0; c < 2; ++c)
        aSrc[c] = vf + (size_t)(m0 + c * 16 + subrow) * D + kbeg + qstg * 8;
    #pragma unroll
    for (int c = 0; c < 4; ++c)
        bSrc[c] = W  + (size_t)(n0 + c * 16 + subrow) * D + kbeg + qstg * 8;

    // ---- fragment read offsets ----
    const int r16 = L & 15;
    const int quad = L >> 4;
    const int swz = quad ^ (r16 & 3) ^ ((r16 >> 2) & 3);
    const int aoff = r16 * 64 + swz * 16;   // byte offset within a buffer

    f32x4 acc[2][4] = {};

    auto issue = [&](int step, int buf) {
        const size_t koff = (size_t)step * 32;   // elements
        #pragma unroll
        for (int c = 0; c < 2; ++c)
            __builtin_amdgcn_global_load_lds(
                (gbl_void*)(aSrc[c] + koff),
                (lds_void*)(stg + buf * 2048 + c * 1024), 16, 0, 0);
        #pragma unroll
        for (int c = 0; c < 4; ++c)
            __builtin_amdgcn_global_load_lds(
                (gbl_void*)(bSrc[c] + koff),
                (lds_void*)(stg + 4096 + buf * 4096 + c * 1024), 16, 0, 0);
    };

    issue(0, 0);
    issue(1, 1);

    // waitcnt imm (gfx9): vmcnt split [3:0]+[15:14], exp [6:4], lgkm [11:8].
    //   vmcnt(6)=0x0F76, vmcnt(0)=0x0F70
    #define GSTEP(S, WC, ISS)                                                  \
    {                                                                          \
        const int buf_ = (S) & 1;                                              \
        __builtin_amdgcn_s_waitcnt(WC);                                        \
        bf16x8 af[2], bg[4];                                                   \
        _Pragma("unroll")                                                      \
        for (int i = 0; i < 2; ++i)                                            \
            af[i] = *(const bf16x8*)(stg + buf_ * 2048 + i * 1024 + aoff);     \
        _Pragma("unroll")                                                      \
        for (int j = 0; j < 4; ++j)                                            \
            bg[j] = *(const bf16x8*)(stg + 4096 + buf_ * 4096 + j * 1024 + aoff); \
        _Pragma("unroll")                                                      \
        for (int i = 0; i < 2; ++i)                                            \
            _Pragma("unroll")                                                  \
            for (int j = 0; j < 4; ++j)                                        \
                acc[i][j] = __builtin_amdgcn_mfma_f32_16x16x32_bf16(           \
                    af[i], bg[j], acc[i][j], 0, 0, 0);                         \
        if (ISS) issue((S) + DEPTH, buf_);                                     \
    }

    #pragma unroll 1
    for (int s = 0; s < NSTEP - 1; ++s)
        GSTEP(s, 0x0F76, s + DEPTH < NSTEP);   // steady: vmcnt(6)
    GSTEP(NSTEP - 1, 0x0F70, false);           // vmcnt(0): staging drained
    #undef GSTEP

    // ---- in-block 8-wave K-reduction + bias + emb16 + positive partial ----
    __syncthreads();   // all waves done with staging LDS
    float* ctw = (float*)smem + w * 2208;      // 32x69 f32, conflict-free
    #pragma unroll
    for (int i = 0; i < 2; ++i)
        #pragma unroll
        for (int j = 0; j < 4; ++j)
            #pragma unroll
            for (int r = 0; r < 4; ++r)
                ctw[(i * 16 + quad * 4 + r) * 69 + (j * 16 + r16)] = acc[i][j][r];
    __syncthreads();

    const int row = t >> 4;            // 0..31
    const int cb  = (t & 15) * 4;      // 0..60
    const float* base = (const float*)smem + row * 69 + cb;
    float s[4];
    #pragma unroll
    for (int u = 0; u < 4; ++u) {
        float a01 = (base[u] + base[2208 + u]) + (base[4416 + u] + base[6624 + u]);
        float a23 = (base[8832 + u] + base[11040 + u]) + (base[13248 + u] + base[15456 + u]);
        s[u] = a01 + a23;
    }
    const float4 bl = *(const float4*)(bias + n0 + cb);
    s[0] += bl.x; s[1] += bl.y; s[2] += bl.z; s[3] += bl.w;

    const size_t obase = (size_t)(m0 + row) * E + n0 + cb;
    h4 o;
    o[0] = (_Float16)s[0]; o[1] = (_Float16)s[1];
    o[2] = (_Float16)s[2]; o[3] = (_Float16)s[3];
    *(h4*)(emb16 + obase) = o;

    const float4 pl = *(const float4*)(p_lfs + obase);
    float d, a = 0.f;
    d = pl.x - s[0]; d = fmaxf(d, 0.f); a = fmaf(d, d, a);
    d = pl.y - s[1]; d = fmaxf(d, 0.f); a = fmaf(d, d, a);
    d = pl.z - s[2]; d = fmaxf(d, 0.f); a = fmaf(d, d, a);
    d = pl.w - s[3]; d = fmaxf(d, 0.f); a = fmaf(d, d, a);
    #pragma unroll
    for (int off = 8; off; off >>= 1) a += __shfl_down(a, off, 16);
    if ((t & 15) == 0) atomicAdd(psum + m0 + row, a);
}

// ---------------------------------------------------------------------------
// Kernel 2: neg-score partials, f16 math with v_dot2_f32_f16 (f32 accum).
// grid (8,8,8) = 512 blocks. Tile 64(b) x 64(n), 4x4 f32 accs/thread,
// one EC=128 chunk per block. n_lfs read as f32 and converted in-stage
// (r7: n16 buffer + cvt segment eliminated). eS stores NEGATED emb.
// pn stored f16 (chunk sums ~128, ulp 0.0625 -> final err ~4e-3 << thr).
// ---------------------------------------------------------------------------
__global__ __launch_bounds__(256, 4) void scores_part(
    const _Float16* __restrict__ emb16,  // [B, E] f16
    const float* __restrict__ n_lfs,     // [N, E] f32
    _Float16* __restrict__ pn)           // [ES, B, N] f16
{
    constexpr int LDH = EC + 8;  // 136 halfs
    __shared__ _Float16 eS[64 * LDH];
    __shared__ _Float16 nS[64 * LDH];

    const int t  = threadIdx.x;
    const int n0 = blockIdx.x * 64;
    const int b0 = blockIdx.y * 64;
    const int e0 = blockIdx.z * EC;

    {
        const int row = t >> 2;            // 0..63
        const int cb  = (t & 3) * 32;      // halfs: 0,32,64,96
        const _Float16* ep = emb16 + (size_t)(b0 + row) * E + e0 + cb;
        const float*    np = n_lfs + (size_t)(n0 + row) * E + e0 + cb;
        _Float16* ed = &eS[row * LDH + cb];
        _Float16* nd = &nS[row * LDH + cb];
        #pragma unroll
        for (int q = 0; q < 4; ++q) {
            h8 v = *(const h8*)(ep + q * 8);
            float4 w0 = *(const float4*)(np + q * 8);
            float4 w1 = *(const float4*)(np + q * 8 + 4);
            h8 wv;
            wv[0] = (_Float16)w0.x; wv[1] = (_Float16)w0.y;
            wv[2] = (_Float16)w0.z; wv[3] = (_Float16)w0.w;
            wv[4] = (_Float16)w1.x; wv[5] = (_Float16)w1.y;
            wv[6] = (_Float16)w1.z; wv[7] = (_Float16)w1.w;
            *(h8*)(ed + q * 8) = -v;       // pre-negated emb
            *(h8*)(nd + q * 8) = wv;
        }
    }
    __syncthreads();

    const int ty = t >> 4;   // 0..15 -> b rows ty+16r
    const int tx = t & 15;   // 0..15 -> n rows tx+16q

    float acc[4][4] = {};
    const h4 z4 = {};

    #pragma unroll 2
    for (int e = 0; e < EC; e += 4) {
        h4 a[4], c[4];
        #pragma unroll
        for (int r = 0; r < 4; ++r)
            a[r] = *(const h4*)&eS[(ty + 16 * r) * LDH + e];
        #pragma unroll
        for (int q = 0; q < 4; ++q)
            c[q] = *(const h4*)&nS[(tx + 16 * q) * LDH + e];
        #pragma unroll
        for (int r = 0; r < 4; ++r)
            #pragma unroll
            for (int q = 0; q < 4; ++q) {
                h4 d = c[q] + a[r];                       // n - e
                d = __builtin_elementwise_max(d, z4);     // relu
                h2 dl = __builtin_shufflevector(d, d, 0, 1);
                h2 dh = __builtin_shufflevector(d, d, 2, 3);
                acc[r][q] = fdot2(dl, dl, acc[r][q]);
                acc[r][q] = fdot2(dh, dh, acc[r][q]);
            }
    }

    _Float16* po = pn + (size_t)blockIdx.z * B * N;
    #pragma unroll
    for (int r = 0; r < 4; ++r) {
        const size_t ob = (size_t)(b0 + ty + 16 * r) * N;
        #pragma unroll
        for (int q = 0; q < 4; ++q)
            po[ob + n0 + tx + 16 * q] = (_Float16)acc[r][q];
    }
}

// ---------------------------------------------------------------------------
// Kernel 3: negative-score reduce over ES parts + positive -sqrt from psum.
// grid 1026: [0,1024) negatives, [1024,1026) positives.
// ---------------------------------------------------------------------------
__global__ __launch_bounds__(256) void scores_final(
    const _Float16* __restrict__ pn,  // [ES, B, N] f16
    const float* __restrict__ psum,   // [B] f32
    float* __restrict__ out)          // [B, 1+N]
{
    if (blockIdx.x >= 1024) {
        const int idx = (blockIdx.x - 1024) * 256 + threadIdx.x;  // 0..511
        out[(size_t)idx * 513] = -sqrtf(psum[idx]);
        return;
    }
    const int i = blockIdx.x * 256 + threadIdx.x;   // 0..B*N-1
    const int b = i >> 9;                           // /N
    const int n = i & (N - 1);
    float s = 0.f;
    #pragma unroll
    for (int z = 0; z < ES; ++z)
        s += (float)pn[(size_t)z * B * N + i];
    out[(size_t)b * 513 + 1 + n] = -sqrtf(s);
}

extern "C" void kernel_launch(void* const* d_in, const int* in_sizes, int n_in,
                              void* d_out, int out_size, void* d_ws, size_t ws_size,
                              hipStream_t stream) {
    const float* vf    = (const float*)d_in[0];  // [512,4096] f32
    const float* p_lfs = (const float*)d_in[1];  // [512,1024] f32
    const float* n_lfs = (const float*)d_in[2];  // [512,1024] f32
    const float* W     = (const float*)d_in[3];  // [1024,4096] f32
    const float* bias  = (const float*)d_in[4];  // [1024] f32
    float* out = (float*)d_out;                  // [512,513] f32

    // ws layout (18 MB peak):
    //   [0,  4MB): pn    f16 [ES=8,512,512]
    //   [4,  8MB): vfB   bf16 [512,4096]
    //   [8, 16MB): WB    bf16 [1024,4096]
    //   [16,17MB): emb16 f16 [512,1024]
    //   [17MB, +2KB): psum f32 [512]
    char* ws = (char*)d_ws;
    _Float16*       pn    = (_Float16*)ws;
    unsigned short* vfB   = (unsigned short*)(ws + ((size_t)4 << 20));
    unsigned short* WB    = (unsigned short*)(ws + ((size_t)8 << 20));
    _Float16*       emb16 = (_Float16*)(ws + ((size_t)16 << 20));
    float*          psum  = (float*)(ws + ((size_t)17 << 20));

    cvt_all<<<3073, 256, 0, stream>>>(vf, W, vfB, WB, psum);

    gemm_fused<<<256, 512, 0, stream>>>(vfB, WB, bias, p_lfs, emb16, psum);

    dim3 g3(N / 64, B / 64, ES);   // (8, 8, 8) = 512 blocks
    scores_part<<<g3, 256, 0, stream>>>(emb16, n_lfs, pn);

    scores_final<<<1026, 256, 0, stream>>>(pn, psum, out);
}

// Round 8
// 115.353 us; speedup vs baseline: 1.0033x; 1.0033x over previous
//
#include <hip/hip_runtime.h>
#include <hip/hip_bf16.h>

// Problem constants (fixed by setup_inputs)
constexpr int B = 512;   // batch
constexpr int D = 4096;  // D_vis
constexpr int E = 1024;  // embed dim
constexpr int N = 512;   // negatives
constexpr int KSW = 16;  // total K-chunks (one per wave)
constexpr int KSG = 4;   // global partial slices (after in-block 4-wave reduce)
constexpr int KC = D / KSW;     // 256 K per wave
constexpr int NSTEP = KC / 32;  // 8 k-steps per wave
constexpr int ES = 8;    // scores E-chunk count
constexpr int EC = E / ES;      // 128 e per chunk
constexpr int DEPTH = 2;        // GEMM pipeline depth per wave

typedef __attribute__((ext_vector_type(8))) short bf16x8;   // 8 bf16 = 4 VGPRs
typedef __attribute__((ext_vector_type(4))) float f32x4;
typedef _Float16 h2 __attribute__((ext_vector_type(2)));
typedef _Float16 h4 __attribute__((ext_vector_type(4)));
typedef _Float16 h8 __attribute__((ext_vector_type(8)));

typedef __attribute__((address_space(3))) void lds_void;
typedef const __attribute__((address_space(1))) void gbl_void;

__device__ __forceinline__ unsigned short f2bf(float f) {
    __hip_bfloat16 h = __float2bfloat16(f);   // RTNE
    return *reinterpret_cast<unsigned short*>(&h);
}

#if __has_builtin(__builtin_amdgcn_fdot2)
__device__ __forceinline__ float fdot2(h2 a, h2 b, float c) {
    return __builtin_amdgcn_fdot2(a, b, c, false);
}
#else
__device__ __forceinline__ float fdot2(h2 a, h2 b, float c) {
    return c + (float)a[0] * (float)b[0] + (float)a[1] * (float)b[1];
}
#endif

// ---------------------------------------------------------------------------
// Kernel 0: f32 -> bf16 convert for vf and W, f32 -> f16 for n_lfs.
// grid 3328: [0,1024) vf, [1024,3072) W, [3072,3328) n_lfs.
// ---------------------------------------------------------------------------
__global__ __launch_bounds__(256) void cvt_all(
    const float* __restrict__ vf, const float* __restrict__ W,
    const float* __restrict__ n_lfs,
    unsigned short* __restrict__ vfB, unsigned short* __restrict__ WB,
    _Float16* __restrict__ n16)
{
    const int bid = blockIdx.x;
    if (bid < 3072) {
        const float* src;
        unsigned short* dst;
        int i;
        if (bid < 1024) { src = vf; dst = vfB; i = (bid * 256 + threadIdx.x) * 8; }
        else           { src = W;  dst = WB;  i = ((bid - 1024) * 256 + threadIdx.x) * 8; }
        float4 v0 = *(const float4*)(src + i);
        float4 v1 = *(const float4*)(src + i + 4);
        bf16x8 o;
        o[0] = (short)f2bf(v0.x); o[1] = (short)f2bf(v0.y);
        o[2] = (short)f2bf(v0.z); o[3] = (short)f2bf(v0.w);
        o[4] = (short)f2bf(v1.x); o[5] = (short)f2bf(v1.y);
        o[6] = (short)f2bf(v1.z); o[7] = (short)f2bf(v1.w);
        *(bf16x8*)(dst + i) = o;
    } else {
        const int i = ((bid - 3072) * 256 + threadIdx.x) * 8;
        float4 v0 = *(const float4*)(n_lfs + i);
        float4 v1 = *(const float4*)(n_lfs + i + 4);
        h8 o;
        o[0] = (_Float16)v0.x; o[1] = (_Float16)v0.y;
        o[2] = (_Float16)v0.z; o[3] = (_Float16)v0.w;
        o[4] = (_Float16)v1.x; o[5] = (_Float16)v1.y;
        o[6] = (_Float16)v1.z; o[7] = (_Float16)v1.w;
        *(h8*)(n16 + i) = o;
    }
}

// ---------------------------------------------------------------------------
// Kernel 1: K-split GEMM with in-block K-reduction (r6 structure, VERIFIED
// 113.4us total; r7's 32-wide tile doubled B re-staging 8x->16x (+64MB L2)
// and regressed -- tile stays 64x64).
// grid (16,8,4) = 512 blocks x 4 waves (256 thr) = 2048 waves = 8 waves/CU.
// Wave w of block z handles k-chunk ks = z*4+w (KC=256): per-wave pipeline,
// own 16KB staging, DEPTH=2, steady vmcnt(8), last step vmcnt(0).
// Epilogue: barrier -> 4 per-wave 64x69 f32 transpose buffers (69%32=5,
// gcd(5,32)=1 -> conflict-free; 4x17664B=69KB overlays dead staging) ->
// barrier -> 256 threads sum 4 partials in f32, pack f16, coalesced stores.
//  XCD swizzle: l=(id%8)*64+id/8; z=l>>7, n0=(l&15)*64, m0=((l>>4)&7)*64.
// C/D: col=lane&15, row=quad*4+reg  [verified prior session]
// ---------------------------------------------------------------------------
__global__ __launch_bounds__(256) void gemm_lds(
    const unsigned short* __restrict__ vf,    // [B, D] bf16 bits
    const unsigned short* __restrict__ W,     // [E, D] bf16 bits
    _Float16* __restrict__ part)              // [KSG, B, E] f16
{
    __shared__ __align__(16) char smem[70656];

    const int t = threadIdx.x;
    const int w = t >> 6;        // wave 0..3
    const int L = t & 63;

    const int id = blockIdx.x + 16 * blockIdx.y + 128 * blockIdx.z;
    const int l  = (id & 7) * 64 + (id >> 3);
    const int z  = l >> 7;             // 0..3 global partial slice
    const int n0 = (l & 15) * 64;
    const int m0 = ((l >> 4) & 7) * 64;

    char* stg = smem + w * 16384;      // this wave's staging base

    // ---- staging addresses ----
    const int subrow = L >> 2;                                  // 0..15
    const int qstg = (L & 3) ^ ((L >> 2) & 3) ^ ((L >> 4) & 3); // swizzled k-group
    const int kbeg = (z * 4 + w) * KC;
    const unsigned short* aSrc[4];
    const unsigned short* bSrc[4];
    #pragma unroll
    for (int c = 0; c < 4; ++c) {
        aSrc[c] = vf + (size_t)(m0 + c * 16 + subrow) * D + kbeg + qstg * 8;
        bSrc[c] = W  + (size_t)(n0 + c * 16 + subrow) * D + kbeg + qstg * 8;
    }

    // ---- fragment read offsets ----
    const int r16 = L & 15;
    const int quad = L >> 4;
    const int swz = quad ^ (r16 & 3) ^ ((r16 >> 2) & 3);
    const int aoff = r16 * 64 + swz * 16;   // byte offset within a buffer

    f32x4 acc[4][4] = {};

    auto issue = [&](int step, int buf) {
        const size_t koff = (size_t)step * 32;   // elements
        #pragma unroll
        for (int c = 0; c < 4; ++c) {
            __builtin_amdgcn_global_load_lds(
                (gbl_void*)(aSrc[c] + koff),
                (lds_void*)(stg + buf * 4096 + c * 1024), 16, 0, 0);
            __builtin_amdgcn_global_load_lds(
                (gbl_void*)(bSrc[c] + koff),
                (lds_void*)(stg + 8192 + buf * 4096 + c * 1024), 16, 0, 0);
        }
    };

    issue(0, 0);
    issue(1, 1);

    // waitcnt imm (gfx9): vmcnt split [3:0]+[15:14], exp [6:4], lgkm [11:8].
    //   vmcnt(8)=0x0F78, vmcnt(0)=0x0F70
    #define GSTEP(S, WC, ISS)                                                  \
    {                                                                          \
        const int buf_ = (S) & 1;                                              \
        __builtin_amdgcn_s_waitcnt(WC);                                        \
        bf16x8 af[4], bg[4];                                                   \
        _Pragma("unroll")                                                      \
        for (int i = 0; i < 4; ++i)                                            \
            af[i] = *(const bf16x8*)(stg + buf_ * 4096 + i * 1024 + aoff);     \
        _Pragma("unroll")                                                      \
        for (int j = 0; j < 4; ++j)                                            \
            bg[j] = *(const bf16x8*)(stg + 8192 + buf_ * 4096 + j * 1024 + aoff); \
        _Pragma("unroll")                                                      \
        for (int i = 0; i < 4; ++i)                                            \
            _Pragma("unroll")                                                  \
            for (int j = 0; j < 4; ++j)                                        \
                acc[i][j] = __builtin_amdgcn_mfma_f32_16x16x32_bf16(           \
                    af[i], bg[j], acc[i][j], 0, 0, 0);                         \
        if (ISS) issue((S) + DEPTH, buf_);                                     \
    }

    #pragma unroll 1
    for (int s = 0; s < NSTEP - 1; ++s)
        GSTEP(s, 0x0F78, s + DEPTH < NSTEP);   // steady: vmcnt(8)
    GSTEP(NSTEP - 1, 0x0F70, false);           // vmcnt(0): staging drained
    #undef GSTEP

    // ---- in-block 4-wave reduction + coalesced f16 store ----
    __syncthreads();   // all waves done with staging LDS (vmcnt(0) + lgkm)
    float* ctw = (float*)smem + w * 4416;      // 64x69 f32, conflict-free
    #pragma unroll
    for (int i = 0; i < 4; ++i)
        #pragma unroll
        for (int j = 0; j < 4; ++j)
            #pragma unroll
            for (int r = 0; r < 4; ++r)
                ctw[(i * 16 + quad * 4 + r) * 69 + (j * 16 + r16)] = acc[i][j][r];
    __syncthreads();

    const int row = t >> 2;            // 0..63
    const int cb  = (t & 3) * 16;      // 0,16,32,48
    const float* p0 = (const float*)smem + row * 69 + cb;
    float s[16];
    #pragma unroll
    for (int u = 0; u < 16; ++u)
        s[u] = (p0[u] + p0[4416 + u]) + (p0[8832 + u] + p0[13248 + u]);
    _Float16* po = part + (size_t)z * B * E + (size_t)(m0 + row) * E + n0 + cb;
    h8 v0, v1;
    #pragma unroll
    for (int u = 0; u < 8; ++u) { v0[u] = (_Float16)s[u]; v1[u] = (_Float16)s[u + 8]; }
    *(h8*)po = v0;
    *(h8*)(po + 8) = v1;
}

// ---------------------------------------------------------------------------
// Kernel 2: one block per batch row b (grid = 512):
//   s = sum_ks part[ks][b][:] + bias  -> emb16[b][:] (f16)
//   p_score[b] = -||relu(p_lfs[b] - s)|| -> out[b*513]  (s in full f32)
// ---------------------------------------------------------------------------
__global__ __launch_bounds__(256) void reduce_emb(
    const _Float16* __restrict__ part, const float* __restrict__ bias,
    const float* __restrict__ p_lfs,
    _Float16* __restrict__ emb16, float* __restrict__ out)
{
    const int b = blockIdx.x;
    const int e = threadIdx.x * 4;
    const size_t base = (size_t)b * E + e;
    float4 s = *(const float4*)(bias + e);
    #pragma unroll
    for (int ks = 0; ks < KSG; ++ks) {
        h4 p = *(const h4*)(part + (size_t)ks * B * E + base);
        s.x += (float)p[0]; s.y += (float)p[1];
        s.z += (float)p[2]; s.w += (float)p[3];
    }
    h4 o;
    o[0] = (_Float16)s.x; o[1] = (_Float16)s.y;
    o[2] = (_Float16)s.z; o[3] = (_Float16)s.w;
    *(h4*)(emb16 + base) = o;

    // positive score for row b
    const float4 pl = *(const float4*)(p_lfs + base);
    float d, a = 0.f;
    d = pl.x - s.x; d = fmaxf(d, 0.f); a = fmaf(d, d, a);
    d = pl.y - s.y; d = fmaxf(d, 0.f); a = fmaf(d, d, a);
    d = pl.z - s.z; d = fmaxf(d, 0.f); a = fmaf(d, d, a);
    d = pl.w - s.w; d = fmaxf(d, 0.f); a = fmaf(d, d, a);
    #pragma unroll
    for (int off = 32; off; off >>= 1) a += __shfl_down(a, off, 64);
    __shared__ float red[4];
    if ((threadIdx.x & 63) == 0) red[threadIdx.x >> 6] = a;
    __syncthreads();
    if (threadIdx.x == 0)
        out[(size_t)b * 513] = -sqrtf(red[0] + red[1] + red[2] + red[3]);
}

// ---------------------------------------------------------------------------
// Kernel 3 (r8): FUSED negative scores -- full E in-block, no pn buffer.
// grid (N/32, B/16) = (16,32) = 512 blocks x 256 thr = 2 blocks/CU
// (8 waves/CU = 2/SIMD, same TLP as the old scores_part).
// Tile 16(b) x 32(n); loop over ES=8 e-chunks with double-buffered LDS
// (2 x 13.3KB = 26.6KB), f32 accumulation across the whole E=1024, then
// -sqrt and direct store to out. Eliminates pn (4MB write + 4MB read) and
// the scores_final dispatch; precision improves (no f16 partial rounding).
// eS rows are broadcast reads; nS stride 140 halfs (tx*70%32, gcd=2 ->
// 2 distinct addrs/bank = free). nS written as h4 pairs (280B row stride
// is 8B- but not 16B-aligned).
// ---------------------------------------------------------------------------
__global__ __launch_bounds__(256, 2) void scores_fused(
    const _Float16* __restrict__ emb16,  // [B, E] f16
    const _Float16* __restrict__ n16,    // [N, E] f16
    float* __restrict__ out)             // [B, 1+N]
{
    constexpr int SB = 16, SN = 32;
    constexpr int LDHE = 136;  // eS row stride (halfs), 272B 16B-aligned
    constexpr int LDHN = 140;  // nS row stride (halfs), 280B

    __shared__ _Float16 eS[2][SB * LDHE];
    __shared__ _Float16 nS[2][SN * LDHN];

    const int t  = threadIdx.x;
    const int n0 = blockIdx.x * SN;
    const int b0 = blockIdx.y * SB;

    // staging split: 256 thr cover eS 16x128 (1 h8 each) + nS 32x128 (2 h8 each)
    const int er = t >> 4;           // 0..15
    const int ec = (t & 15) * 8;     // 0..120
    const int nr = t >> 3;           // 0..31
    const int nc = (t & 7) * 16;     // 0..112

    auto stage = [&](int c, int buf) {
        const int e0 = c * EC;
        h8 v = *(const h8*)(emb16 + (size_t)(b0 + er) * E + e0 + ec);
        *(h8*)&eS[buf][er * LDHE + ec] = -v;   // pre-negated emb
        h8 w0 = *(const h8*)(n16 + (size_t)(n0 + nr) * E + e0 + nc);
        h8 w1 = *(const h8*)(n16 + (size_t)(n0 + nr) * E + e0 + nc + 8);
        _Float16* nd = &nS[buf][nr * LDHN + nc];
        *(h4*)(nd)      = __builtin_shufflevector(w0, w0, 0, 1, 2, 3);
        *(h4*)(nd + 4)  = __builtin_shufflevector(w0, w0, 4, 5, 6, 7);
        *(h4*)(nd + 8)  = __builtin_shufflevector(w1, w1, 0, 1, 2, 3);
        *(h4*)(nd + 12) = __builtin_shufflevector(w1, w1, 4, 5, 6, 7);
    };

    const int tx = t & 31;   // n col
    const int ty = t >> 5;   // 0..7 -> b rows ty and ty+8

    float acc0 = 0.f, acc1 = 0.f;
    const h4 z4 = {};

    stage(0, 0);
    __syncthreads();

    #pragma unroll 1
    for (int c = 0; c < ES; ++c) {
        const int buf = c & 1;
        if (c + 1 < ES) stage(c + 1, buf ^ 1);   // overlap with compute

        #pragma unroll 4
        for (int e = 0; e < EC; e += 4) {
            h4 a0 = *(const h4*)&eS[buf][ty * LDHE + e];
            h4 a1 = *(const h4*)&eS[buf][(ty + 8) * LDHE + e];
            h4 cc = *(const h4*)&nS[buf][tx * LDHN + e];
            h4 d0 = cc + a0;                         // n - e (eS negated)
            h4 d1 = cc + a1;
            d0 = __builtin_elementwise_max(d0, z4);  // relu
            d1 = __builtin_elementwise_max(d1, z4);
            h2 d0l = __builtin_shufflevector(d0, d0, 0, 1);
            h2 d0h = __builtin_shufflevector(d0, d0, 2, 3);
            h2 d1l = __builtin_shufflevector(d1, d1, 0, 1);
            h2 d1h = __builtin_shufflevector(d1, d1, 2, 3);
            acc0 = fdot2(d0l, d0l, acc0);
            acc0 = fdot2(d0h, d0h, acc0);
            acc1 = fdot2(d1l, d1l, acc1);
            acc1 = fdot2(d1h, d1h, acc1);
        }
        __syncthreads();
    }

    out[(size_t)(b0 + ty) * 513 + 1 + n0 + tx]     = -sqrtf(acc0);
    out[(size_t)(b0 + ty + 8) * 513 + 1 + n0 + tx] = -sqrtf(acc1);
}

extern "C" void kernel_launch(void* const* d_in, const int* in_sizes, int n_in,
                              void* d_out, int out_size, void* d_ws, size_t ws_size,
                              hipStream_t stream) {
    const float* vf    = (const float*)d_in[0];  // [512,4096] f32
    const float* p_lfs = (const float*)d_in[1];  // [512,1024] f32
    const float* n_lfs = (const float*)d_in[2];  // [512,1024] f32
    const float* W     = (const float*)d_in[3];  // [1024,4096] f32
    const float* bias  = (const float*)d_in[4];  // [1024] f32
    float* out = (float*)d_out;                  // [512,513] f32

    // ws layout (18 MB peak):
    //   [0,  4MB): pg    f16 [KSG=4,512,1024]
    //   [4,  8MB): vfB   bf16 [512,4096]
    //   [8, 16MB): WB    bf16 [1024,4096]
    //   [16,17MB): emb16 f16 [512,1024]
    //   [17,18MB): n16   f16 [512,1024]
    char* ws = (char*)d_ws;
    _Float16*       pg    = (_Float16*)ws;
    unsigned short* vfB   = (unsigned short*)(ws + ((size_t)4 << 20));
    unsigned short* WB    = (unsigned short*)(ws + ((size_t)8 << 20));
    _Float16*       emb16 = (_Float16*)(ws + ((size_t)16 << 20));
    _Float16*       n16   = (_Float16*)(ws + ((size_t)17 << 20));

    cvt_all<<<3328, 256, 0, stream>>>(vf, W, n_lfs, vfB, WB, n16);

    dim3 g1(E / 64, B / 64, KSG);  // (16, 8, 4) = 512 four-wave blocks
    gemm_lds<<<g1, 256, 0, stream>>>(vfB, WB, pg);

    reduce_emb<<<B, 256, 0, stream>>>(pg, bias, p_lfs, emb16, out);

    dim3 g3(N / 32, B / 16);       // (16, 32) = 512 blocks
    scores_fused<<<g3, 256, 0, stream>>>(emb16, n16, out);
}

// Round 9
// 112.880 us; speedup vs baseline: 1.0253x; 1.0219x over previous
//
#include <hip/hip_runtime.h>
#include <hip/hip_bf16.h>

// Problem constants (fixed by setup_inputs)
constexpr int B = 512;   // batch
constexpr int D = 4096;  // D_vis
constexpr int E = 1024;  // embed dim
constexpr int N = 512;   // negatives
constexpr int KSW = 16;  // total K-chunks (one per wave)
constexpr int KSG = 4;   // global partial slices (after in-block 4-wave reduce)
constexpr int KC = D / KSW;     // 256 K per wave
constexpr int NSTEP = KC / 32;  // 8 k-steps per wave
constexpr int ES = 8;    // scores E-split factor
constexpr int EC = E / ES;      // 128 e per scores block
constexpr int DEPTH = 2;        // GEMM pipeline depth per wave

typedef __attribute__((ext_vector_type(8))) short bf16x8;   // 8 bf16 = 4 VGPRs
typedef __attribute__((ext_vector_type(4))) float f32x4;
typedef _Float16 h2 __attribute__((ext_vector_type(2)));
typedef _Float16 h4 __attribute__((ext_vector_type(4)));
typedef _Float16 h8 __attribute__((ext_vector_type(8)));

typedef __attribute__((address_space(3))) void lds_void;
typedef const __attribute__((address_space(1))) void gbl_void;

__device__ __forceinline__ unsigned short f2bf(float f) {
    __hip_bfloat16 h = __float2bfloat16(f);   // RTNE
    return *reinterpret_cast<unsigned short*>(&h);
}

#if __has_builtin(__builtin_amdgcn_fdot2)
__device__ __forceinline__ float fdot2(h2 a, h2 b, float c) {
    return __builtin_amdgcn_fdot2(a, b, c, false);
}
#else
__device__ __forceinline__ float fdot2(h2 a, h2 b, float c) {
    return c + (float)a[0] * (float)b[0] + (float)a[1] * (float)b[1];
}
#endif

// ---------------------------------------------------------------------------
// Kernel 0: f32 -> bf16 convert for vf and W, f32 -> f16 for n_lfs.
// grid 3328: [0,1024) vf, [1024,3072) W, [3072,3328) n_lfs.
// ---------------------------------------------------------------------------
__global__ __launch_bounds__(256) void cvt_all(
    const float* __restrict__ vf, const float* __restrict__ W,
    const float* __restrict__ n_lfs,
    unsigned short* __restrict__ vfB, unsigned short* __restrict__ WB,
    _Float16* __restrict__ n16)
{
    const int bid = blockIdx.x;
    if (bid < 3072) {
        const float* src;
        unsigned short* dst;
        int i;
        if (bid < 1024) { src = vf; dst = vfB; i = (bid * 256 + threadIdx.x) * 8; }
        else           { src = W;  dst = WB;  i = ((bid - 1024) * 256 + threadIdx.x) * 8; }
        float4 v0 = *(const float4*)(src + i);
        float4 v1 = *(const float4*)(src + i + 4);
        bf16x8 o;
        o[0] = (short)f2bf(v0.x); o[1] = (short)f2bf(v0.y);
        o[2] = (short)f2bf(v0.z); o[3] = (short)f2bf(v0.w);
        o[4] = (short)f2bf(v1.x); o[5] = (short)f2bf(v1.y);
        o[6] = (short)f2bf(v1.z); o[7] = (short)f2bf(v1.w);
        *(bf16x8*)(dst + i) = o;
    } else {
        const int i = ((bid - 3072) * 256 + threadIdx.x) * 8;
        float4 v0 = *(const float4*)(n_lfs + i);
        float4 v1 = *(const float4*)(n_lfs + i + 4);
        h8 o;
        o[0] = (_Float16)v0.x; o[1] = (_Float16)v0.y;
        o[2] = (_Float16)v0.z; o[3] = (_Float16)v0.w;
        o[4] = (_Float16)v1.x; o[5] = (_Float16)v1.y;
        o[6] = (_Float16)v1.z; o[7] = (_Float16)v1.w;
        *(h8*)(n16 + i) = o;
    }
}

// ---------------------------------------------------------------------------
// Kernel 1: K-split GEMM with in-block K-reduction (r6 structure, VERIFIED
// best at 113.4us total; r7/r8 structural fusions both regressed by
// destroying tiling reuse -- tile stays 64x64, 4-wave in-block reduce).
// grid (16,8,4) = 512 blocks x 4 waves (256 thr) = 2048 waves = 8 waves/CU.
// Wave w of block z handles k-chunk ks = z*4+w (KC=256): per-wave pipeline,
// own 16KB staging, DEPTH=2, steady vmcnt(8), last step vmcnt(0).
// r9: s_setprio(1) around the MFMA cluster (T5) -- waves here are
// INDEPENDENT (no lockstep barrier in K-loop), the regime where setprio
// paid on attn (m191) vs null on barrier-locked GEMM (m190).
// Epilogue: barrier -> 4 per-wave 64x69 f32 transpose buffers (69%32=5,
// gcd(5,32)=1 -> conflict-free; 4x17664B=69KB overlays dead staging) ->
// barrier -> 256 threads sum 4 partials in f32, pack f16, coalesced stores.
//  XCD swizzle: l=(id%8)*64+id/8; z=l>>7, n0=(l&15)*64, m0=((l>>4)&7)*64.
// C/D: col=lane&15, row=quad*4+reg  [verified prior session]
// ---------------------------------------------------------------------------
__global__ __launch_bounds__(256) void gemm_lds(
    const unsigned short* __restrict__ vf,    // [B, D] bf16 bits
    const unsigned short* __restrict__ W,     // [E, D] bf16 bits
    _Float16* __restrict__ part)              // [KSG, B, E] f16
{
    __shared__ __align__(16) char smem[70656];

    const int t = threadIdx.x;
    const int w = t >> 6;        // wave 0..3
    const int L = t & 63;

    const int id = blockIdx.x + 16 * blockIdx.y + 128 * blockIdx.z;
    const int l  = (id & 7) * 64 + (id >> 3);
    const int z  = l >> 7;             // 0..3 global partial slice
    const int n0 = (l & 15) * 64;
    const int m0 = ((l >> 4) & 7) * 64;

    char* stg = smem + w * 16384;      // this wave's staging base

    // ---- staging addresses ----
    const int subrow = L >> 2;                                  // 0..15
    const int qstg = (L & 3) ^ ((L >> 2) & 3) ^ ((L >> 4) & 3); // swizzled k-group
    const int kbeg = (z * 4 + w) * KC;
    const unsigned short* aSrc[4];
    const unsigned short* bSrc[4];
    #pragma unroll
    for (int c = 0; c < 4; ++c) {
        aSrc[c] = vf + (size_t)(m0 + c * 16 + subrow) * D + kbeg + qstg * 8;
        bSrc[c] = W  + (size_t)(n0 + c * 16 + subrow) * D + kbeg + qstg * 8;
    }

    // ---- fragment read offsets ----
    const int r16 = L & 15;
    const int quad = L >> 4;
    const int swz = quad ^ (r16 & 3) ^ ((r16 >> 2) & 3);
    const int aoff = r16 * 64 + swz * 16;   // byte offset within a buffer

    f32x4 acc[4][4] = {};

    auto issue = [&](int step, int buf) {
        const size_t koff = (size_t)step * 32;   // elements
        #pragma unroll
        for (int c = 0; c < 4; ++c) {
            __builtin_amdgcn_global_load_lds(
                (gbl_void*)(aSrc[c] + koff),
                (lds_void*)(stg + buf * 4096 + c * 1024), 16, 0, 0);
            __builtin_amdgcn_global_load_lds(
                (gbl_void*)(bSrc[c] + koff),
                (lds_void*)(stg + 8192 + buf * 4096 + c * 1024), 16, 0, 0);
        }
    };

    issue(0, 0);
    issue(1, 1);

    // waitcnt imm (gfx9): vmcnt split [3:0]+[15:14], exp [6:4], lgkm [11:8].
    //   vmcnt(8)=0x0F78, vmcnt(0)=0x0F70
    #define GSTEP(S, WC, ISS)                                                  \
    {                                                                          \
        const int buf_ = (S) & 1;                                              \
        __builtin_amdgcn_s_waitcnt(WC);                                        \
        bf16x8 af[4], bg[4];                                                   \
        _Pragma("unroll")                                                      \
        for (int i = 0; i < 4; ++i)                                            \
            af[i] = *(const bf16x8*)(stg + buf_ * 4096 + i * 1024 + aoff);     \
        _Pragma("unroll")                                                      \
        for (int j = 0; j < 4; ++j)                                            \
            bg[j] = *(const bf16x8*)(stg + 8192 + buf_ * 4096 + j * 1024 + aoff); \
        __builtin_amdgcn_s_setprio(1);                                         \
        _Pragma("unroll")                                                      \
        for (int i = 0; i < 4; ++i)                                            \
            _Pragma("unroll")                                                  \
            for (int j = 0; j < 4; ++j)                                        \
                acc[i][j] = __builtin_amdgcn_mfma_f32_16x16x32_bf16(           \
                    af[i], bg[j], acc[i][j], 0, 0, 0);                         \
        __builtin_amdgcn_s_setprio(0);                                         \
        if (ISS) issue((S) + DEPTH, buf_);                                     \
    }

    #pragma unroll 1
    for (int s = 0; s < NSTEP - 1; ++s)
        GSTEP(s, 0x0F78, s + DEPTH < NSTEP);   // steady: vmcnt(8)
    GSTEP(NSTEP - 1, 0x0F70, false);           // vmcnt(0): staging drained
    #undef GSTEP

    // ---- in-block 4-wave reduction + coalesced f16 store ----
    __syncthreads();   // all waves done with staging LDS (vmcnt(0) + lgkm)
    float* ctw = (float*)smem + w * 4416;      // 64x69 f32, conflict-free
    #pragma unroll
    for (int i = 0; i < 4; ++i)
        #pragma unroll
        for (int j = 0; j < 4; ++j)
            #pragma unroll
            for (int r = 0; r < 4; ++r)
                ctw[(i * 16 + quad * 4 + r) * 69 + (j * 16 + r16)] = acc[i][j][r];
    __syncthreads();

    const int row = t >> 2;            // 0..63
    const int cb  = (t & 3) * 16;      // 0,16,32,48
    const float* p0 = (const float*)smem + row * 69 + cb;
    float s[16];
    #pragma unroll
    for (int u = 0; u < 16; ++u)
        s[u] = (p0[u] + p0[4416 + u]) + (p0[8832 + u] + p0[13248 + u]);
    _Float16* po = part + (size_t)z * B * E + (size_t)(m0 + row) * E + n0 + cb;
    h8 v0, v1;
    #pragma unroll
    for (int u = 0; u < 8; ++u) { v0[u] = (_Float16)s[u]; v1[u] = (_Float16)s[u + 8]; }
    *(h8*)po = v0;
    *(h8*)(po + 8) = v1;
}

// ---------------------------------------------------------------------------
// Kernel 2: one block per batch row b (grid = 512):
//   s = sum_ks part[ks][b][:] + bias  -> emb16[b][:] (f16)
//   p_score[b] = -||relu(p_lfs[b] - s)|| -> out[b*513]  (s in full f32)
// ---------------------------------------------------------------------------
__global__ __launch_bounds__(256) void reduce_emb(
    const _Float16* __restrict__ part, const float* __restrict__ bias,
    const float* __restrict__ p_lfs,
    _Float16* __restrict__ emb16, float* __restrict__ out)
{
    const int b = blockIdx.x;
    const int e = threadIdx.x * 4;
    const size_t base = (size_t)b * E + e;
    float4 s = *(const float4*)(bias + e);
    #pragma unroll
    for (int ks = 0; ks < KSG; ++ks) {
        h4 p = *(const h4*)(part + (size_t)ks * B * E + base);
        s.x += (float)p[0]; s.y += (float)p[1];
        s.z += (float)p[2]; s.w += (float)p[3];
    }
    h4 o;
    o[0] = (_Float16)s.x; o[1] = (_Float16)s.y;
    o[2] = (_Float16)s.z; o[3] = (_Float16)s.w;
    *(h4*)(emb16 + base) = o;

    // positive score for row b
    const float4 pl = *(const float4*)(p_lfs + base);
    float d, a = 0.f;
    d = pl.x - s.x; d = fmaxf(d, 0.f); a = fmaf(d, d, a);
    d = pl.y - s.y; d = fmaxf(d, 0.f); a = fmaf(d, d, a);
    d = pl.z - s.z; d = fmaxf(d, 0.f); a = fmaf(d, d, a);
    d = pl.w - s.w; d = fmaxf(d, 0.f); a = fmaf(d, d, a);
    #pragma unroll
    for (int off = 32; off; off >>= 1) a += __shfl_down(a, off, 64);
    __shared__ float red[4];
    if ((threadIdx.x & 63) == 0) red[threadIdx.x >> 6] = a;
    __syncthreads();
    if (threadIdx.x == 0)
        out[(size_t)b * 513] = -sqrtf(red[0] + red[1] + red[2] + red[3]);
}

// ---------------------------------------------------------------------------
// Kernel 3: neg-score partials, f16 math with v_dot2_f32_f16 (f32 accum).
// grid (8,8,8) = 512 blocks. Tile 64(b) x 64(n), 4x4 f32 accs/thread,
// one EC=128 chunk per block (r6-verified structure).
// r9: h8 (ds_read_b128) fragment reads -- same VALU count, HALF the LDS
// instruction count. Stride 272B keeps free 2-way bank aliasing
// (4*row mod 32; rows r / r+8 pair) and 16B alignment (272 = 17*16).
// pn stored f16 (chunk sums ~128, ulp 0.0625 -> final err ~4e-3 << thr).
// ---------------------------------------------------------------------------
__global__ __launch_bounds__(256, 4) void scores_part(
    const _Float16* __restrict__ emb16,  // [B, E] f16
    const _Float16* __restrict__ n16,    // [N, E] f16
    _Float16* __restrict__ pn)           // [ES, B, N] f16
{
    constexpr int LDH = EC + 8;  // 136 halfs, row stride 272B
    __shared__ _Float16 eS[64 * LDH];
    __shared__ _Float16 nS[64 * LDH];

    const int t  = threadIdx.x;
    const int n0 = blockIdx.x * 64;
    const int b0 = blockIdx.y * 64;
    const int e0 = blockIdx.z * EC;

    {
        const int row = t >> 2;            // 0..63
        const int cb  = (t & 3) * 32;      // halfs: 0,32,64,96
        const _Float16* ep = emb16 + (size_t)(b0 + row) * E + e0 + cb;
        const _Float16* np = n16   + (size_t)(n0 + row) * E + e0 + cb;
        _Float16* ed = &eS[row * LDH + cb];
        _Float16* nd = &nS[row * LDH + cb];
        #pragma unroll
        for (int q = 0; q < 4; ++q) {
            h8 v = *(const h8*)(ep + q * 8);
            h8 w = *(const h8*)(np + q * 8);
            *(h8*)(ed + q * 8) = -v;       // pre-negated emb
            *(h8*)(nd + q * 8) = w;
        }
    }
    __syncthreads();

    const int ty = t >> 4;   // 0..15 -> b rows ty+16r
    const int tx = t & 15;   // 0..15 -> n rows tx+16q

    float acc[4][4] = {};
    const h8 z8 = {};

    #pragma unroll 2
    for (int e = 0; e < EC; e += 8) {
        h8 a[4], c[4];
        #pragma unroll
        for (int r = 0; r < 4; ++r)
            a[r] = *(const h8*)&eS[(ty + 16 * r) * LDH + e];
        #pragma unroll
        for (int q = 0; q < 4; ++q)
            c[q] = *(const h8*)&nS[(tx + 16 * q) * LDH + e];
        #pragma unroll
        for (int r = 0; r < 4; ++r)
            #pragma unroll
            for (int q = 0; q < 4; ++q) {
                h8 d = c[q] + a[r];                       // n - e (eS negated)
                d = __builtin_elementwise_max(d, z8);     // relu
                h2 d0 = __builtin_shufflevector(d, d, 0, 1);
                h2 d1 = __builtin_shufflevector(d, d, 2, 3);
                h2 d2 = __builtin_shufflevector(d, d, 4, 5);
                h2 d3 = __builtin_shufflevector(d, d, 6, 7);
                acc[r][q] = fdot2(d0, d0, acc[r][q]);
                acc[r][q] = fdot2(d1, d1, acc[r][q]);
                acc[r][q] = fdot2(d2, d2, acc[r][q]);
                acc[r][q] = fdot2(d3, d3, acc[r][q]);
            }
    }

    _Float16* po = pn + (size_t)blockIdx.z * B * N;
    #pragma unroll
    for (int r = 0; r < 4; ++r) {
        const size_t ob = (size_t)(b0 + ty + 16 * r) * N;
        #pragma unroll
        for (int q = 0; q < 4; ++q)
            po[ob + n0 + tx + 16 * q] = (_Float16)acc[r][q];
    }
}

// ---------------------------------------------------------------------------
// Kernel 4: negative-score reduce over ES parts (positives done in K2).
// ---------------------------------------------------------------------------
__global__ __launch_bounds__(256) void scores_final(
    const _Float16* __restrict__ pn,  // [ES, B, N] f16
    float* __restrict__ out)          // [B, 1+N]
{
    const int i = blockIdx.x * 256 + threadIdx.x;   // 0..B*N-1
    const int b = i >> 9;                           // /N
    const int n = i & (N - 1);
    float s = 0.f;
    #pragma unroll
    for (int z = 0; z < ES; ++z)
        s += (float)pn[(size_t)z * B * N + i];
    out[(size_t)b * 513 + 1 + n] = -sqrtf(s);
}

extern "C" void kernel_launch(void* const* d_in, const int* in_sizes, int n_in,
                              void* d_out, int out_size, void* d_ws, size_t ws_size,
                              hipStream_t stream) {
    const float* vf    = (const float*)d_in[0];  // [512,4096] f32
    const float* p_lfs = (const float*)d_in[1];  // [512,1024] f32
    const float* n_lfs = (const float*)d_in[2];  // [512,1024] f32
    const float* W     = (const float*)d_in[3];  // [1024,4096] f32
    const float* bias  = (const float*)d_in[4];  // [1024] f32
    float* out = (float*)d_out;                  // [512,513] f32

    // ws layout (22 MB peak):
    //   [0,  4MB): pg    f16 [KSG=4,512,1024]
    //   [4,  8MB): pn    f16 [ES=8,512,512]
    //   [8, 12MB): vfB   bf16 [512,4096]
    //   [12,20MB): WB    bf16 [1024,4096]
    //   [20,21MB): emb16 f16 [512,1024]
    //   [21,22MB): n16   f16 [512,1024]
    char* ws = (char*)d_ws;
    _Float16*       pg    = (_Float16*)ws;
    _Float16*       pn    = (_Float16*)(ws + ((size_t)4 << 20));
    unsigned short* vfB   = (unsigned short*)(ws + ((size_t)8 << 20));
    unsigned short* WB    = (unsigned short*)(ws + ((size_t)12 << 20));
    _Float16*       emb16 = (_Float16*)(ws + ((size_t)20 << 20));
    _Float16*       n16   = (_Float16*)(ws + ((size_t)21 << 20));

    cvt_all<<<3328, 256, 0, stream>>>(vf, W, n_lfs, vfB, WB, n16);

    dim3 g1(E / 64, B / 64, KSG);  // (16, 8, 4) = 512 four-wave blocks
    gemm_lds<<<g1, 256, 0, stream>>>(vfB, WB, pg);

    reduce_emb<<<B, 256, 0, stream>>>(pg, bias, p_lfs, emb16, out);

    dim3 g3(N / 64, B / 64, ES);   // (8, 8, 8) = 512 blocks
    scores_part<<<g3, 256, 0, stream>>>(emb16, n16, pn);

    scores_final<<<(B * N) / 256, 256, 0, stream>>>(pn, out);
}